// Round 4
// baseline (192.437 us; speedup 1.0000x reference)
//
#include <hip/hip_runtime.h>
#include <hip/hip_bf16.h>

#define IN_F   128
#define OUT_F  64

// ---------------------------------------------------------------------------
// K1: h = x @ W  (f32 vector FMA; no f32 MFMA on CDNA4). h stored as bf16.
// Persistent: 512 blocks (2/CU via 66.5 KB LDS), grid-stride over 64-row
// tiles. T14 async-STAGE: next tile's global loads issue before current
// tile's compute; ds_write after the barrier. Bank-conflict-free (verified:
// SQ_LDS_BANK_CONFLICT = 0 with XS_STRIDE=132).
// ---------------------------------------------------------------------------
#define XS_STRIDE 132

__global__ __launch_bounds__(256) void gemm_xw(const float* __restrict__ x,
                                               const float* __restrict__ W,
                                               __hip_bfloat16* __restrict__ h,
                                               int nTiles) {
    __shared__ float Wl[IN_F * OUT_F];      // 32 KB
    __shared__ float xs[64 * XS_STRIDE];    // 33.8 KB

    const int tid = threadIdx.x;

    // Load W once (coalesced float4).
    {
        const float4* Wv = reinterpret_cast<const float4*>(W);
        float4* Wlv = reinterpret_cast<float4*>(Wl);
        #pragma unroll
        for (int i = 0; i < 8; ++i)
            Wlv[tid + i * 256] = Wv[tid + i * 256];
    }

    const int lane = tid & 63;
    const int wave = tid >> 6;
    const int wM = wave >> 1;
    const int wN = wave & 1;
    const int rg = lane >> 3;
    const int cg = lane & 7;
    const int rBase = wM * 32 + rg;         // rows rBase + 8p
    const int c0 = wN * 32 + cg * 4;        // cols c0..c0+3

    // Prologue: stage tile0 into registers.
    int tile = blockIdx.x;
    float4 st[8];
    if (tile < nTiles) {
        const float4* xrow = reinterpret_cast<const float4*>(x + (long)tile * 64 * IN_F);
        #pragma unroll
        for (int i = 0; i < 8; ++i) st[i] = xrow[tid + i * 256];
    }

    while (tile < nTiles) {
        __syncthreads();   // xs free (readers of previous tile done; orders W load on iter 0)
        #pragma unroll
        for (int i = 0; i < 8; ++i) {
            const int j = tid + i * 256;
            *reinterpret_cast<float4*>(&xs[(j >> 5) * XS_STRIDE + (j & 31) * 4]) = st[i];
        }
        __syncthreads();

        // Issue NEXT tile's global loads now; latency hides under compute.
        const int next = tile + gridDim.x;
        if (next < nTiles) {
            const float4* xrow = reinterpret_cast<const float4*>(x + (long)next * 64 * IN_F);
            #pragma unroll
            for (int i = 0; i < 8; ++i) st[i] = xrow[tid + i * 256];
        }

        float acc[4][4];
        #pragma unroll
        for (int p = 0; p < 4; ++p)
            #pragma unroll
            for (int c = 0; c < 4; ++c) acc[p][c] = 0.0f;

        #pragma unroll 2
        for (int k4 = 0; k4 < 32; ++k4) {
            float4 xv[4], wv[4];
            #pragma unroll
            for (int p = 0; p < 4; ++p)
                xv[p] = *reinterpret_cast<const float4*>(&xs[(rBase + 8 * p) * XS_STRIDE + k4 * 4]);
            #pragma unroll
            for (int q = 0; q < 4; ++q)
                wv[q] = *reinterpret_cast<const float4*>(&Wl[(k4 * 4 + q) * OUT_F + c0]);
            #pragma unroll
            for (int p = 0; p < 4; ++p) {
                const float* xp = reinterpret_cast<const float*>(&xv[p]);
                #pragma unroll
                for (int q = 0; q < 4; ++q) {
                    const float xk = xp[q];
                    const float* wq = reinterpret_cast<const float*>(&wv[q]);
                    #pragma unroll
                    for (int c = 0; c < 4; ++c)
                        acc[p][c] = fmaf(xk, wq[c], acc[p][c]);
                }
            }
        }

        // Store h tile as bf16 (4 bf16 = 8 B per store).
        {
            const long row0 = (long)tile * 64;
            __hip_bfloat16* hb = h + (row0 + rBase) * OUT_F + c0;
            #pragma unroll
            for (int p = 0; p < 4; ++p) {
                union { __hip_bfloat16 b[4]; ushort4 u; } cv;
                #pragma unroll
                for (int c = 0; c < 4; ++c) cv.b[c] = __float2bfloat16(acc[p][c]);
                *reinterpret_cast<ushort4*>(&hb[(size_t)(8 * p) * OUT_F]) = cv.u;
            }
        }

        tile = next;
    }
}

// ---------------------------------------------------------------------------
// CSR build: count -> 3-phase multi-block scan -> fill
// ---------------------------------------------------------------------------
__global__ __launch_bounds__(256) void count_edges(const int* __restrict__ edst,
                                                   int* __restrict__ counts,
                                                   int n_edges) {
    const int e = blockIdx.x * 256 + threadIdx.x;
    if (e < n_edges) atomicAdd(&counts[edst[e]], 1);
}

__global__ __launch_bounds__(256) void scan_blocks(const int* __restrict__ counts,
                                                   int* __restrict__ offsets,
                                                   int* __restrict__ blockTotals,
                                                   int n) {
    __shared__ int waveTot[4];
    const int tid = threadIdx.x;
    const int lane = tid & 63;
    const int wave = tid >> 6;
    const int i = blockIdx.x * 256 + tid;

    const int v = (i < n) ? counts[i] : 0;

    int s = v;
    #pragma unroll
    for (int off = 1; off < 64; off <<= 1) {
        const int t = __shfl_up(s, off, 64);
        if (lane >= off) s += t;
    }
    if (lane == 63) waveTot[wave] = s;
    __syncthreads();

    int base = 0;
    #pragma unroll
    for (int w = 0; w < 4; ++w)
        if (w < wave) base += waveTot[w];

    const int incl = s + base;
    if (i < n) offsets[i] = incl - v;
    if (tid == 255) blockTotals[blockIdx.x] = incl;
}

__global__ __launch_bounds__(256) void scan_totals(const int* __restrict__ blockTotals,
                                                   int* __restrict__ blockBases,
                                                   int nb) {
    __shared__ int part[256];
    const int t = threadIdx.x;
    const int v = (t < nb) ? blockTotals[t] : 0;
    part[t] = v;
    __syncthreads();
    for (int off = 1; off < 256; off <<= 1) {
        const int u = (t >= off) ? part[t - off] : 0;
        __syncthreads();
        part[t] += u;
        __syncthreads();
    }
    if (t < nb) blockBases[t] = part[t] - v;
    if (t == nb - 1) blockBases[nb] = part[t];
}

__global__ __launch_bounds__(256) void add_base(int* __restrict__ offsets,
                                                int* __restrict__ cursor,
                                                const int* __restrict__ blockBases,
                                                int n, int nb) {
    const int i = blockIdx.x * 256 + threadIdx.x;
    if (i < n) {
        const int o = offsets[i] + blockBases[blockIdx.x];
        offsets[i] = o;
        cursor[i] = o;
    }
    if (i == 0) offsets[n] = blockBases[nb];
}

__global__ __launch_bounds__(256) void fill_edges(const int* __restrict__ esrc,
                                                  const int* __restrict__ edst,
                                                  int* __restrict__ cursor,
                                                  int* __restrict__ elist,
                                                  int n_edges) {
    const int e = blockIdx.x * 256 + threadIdx.x;
    if (e < n_edges) {
        const int d = edst[e];
        const int slot = atomicAdd(&cursor[d], 1);
        elist[slot] = esrc[e];
    }
}

// ---------------------------------------------------------------------------
// K5: gather + finalize. One wave per dst, lane = feature. h is bf16
// (halves gather traffic: 800K x 128 B random reads, L3-resident).
// ---------------------------------------------------------------------------
__global__ __launch_bounds__(256) void gather_finalize(const __hip_bfloat16* __restrict__ h,
                                                       const int* __restrict__ offsets,
                                                       const int* __restrict__ elist,
                                                       const float* __restrict__ b,
                                                       float* __restrict__ out,
                                                       int n_dst) {
    const int lane = threadIdx.x & 63;
    const int d = blockIdx.x * 4 + (threadIdx.x >> 6);
    if (d >= n_dst) return;

    const int e0 = offsets[d];
    const int e1 = offsets[d + 1];

    float acc = __bfloat162float(h[(size_t)d * OUT_F + lane]);

    for (int base = e0; base < e1; base += 64) {
        const int cnt = min(64, e1 - base);
        const int sidx = (base + lane < e1) ? elist[base + lane] : 0;
        int j = 0;
        for (; j + 4 <= cnt; j += 4) {
            const int s0 = __shfl(sidx, j);
            const int s1 = __shfl(sidx, j + 1);
            const int s2 = __shfl(sidx, j + 2);
            const int s3 = __shfl(sidx, j + 3);
            const float v0 = __bfloat162float(h[(size_t)s0 * OUT_F + lane]);
            const float v1 = __bfloat162float(h[(size_t)s1 * OUT_F + lane]);
            const float v2 = __bfloat162float(h[(size_t)s2 * OUT_F + lane]);
            const float v3 = __bfloat162float(h[(size_t)s3 * OUT_F + lane]);
            acc += (v0 + v1) + (v2 + v3);
        }
        for (; j < cnt; ++j) {
            const int s = __shfl(sidx, j);
            acc += __bfloat162float(h[(size_t)s * OUT_F + lane]);
        }
    }

    const float deg = (float)(e1 - e0);
    out[(size_t)d * OUT_F + lane] = acc / (deg + 1.0f) + b[lane];
}

static inline size_t align256(size_t v) { return (v + 255) & ~(size_t)255; }

extern "C" void kernel_launch(void* const* d_in, const int* in_sizes, int n_in,
                              void* d_out, int out_size, void* d_ws, size_t ws_size,
                              hipStream_t stream) {
    const float* x    = (const float*)d_in[0];
    const int*   esrc = (const int*)d_in[1];
    const int*   edst = (const int*)d_in[2];
    const float* W    = (const float*)d_in[3];
    const float* b    = (const float*)d_in[4];

    const int n_rows  = in_sizes[0] / IN_F;   // 200000
    const int n_edges = in_sizes[1];          // 800000
    const int n_dst   = out_size / OUT_F;     // 50000
    float* out = (float*)d_out;

    const int nScanBlocks = (n_dst + 255) / 256;            // 196

    // Workspace layout (h is bf16 now: 25.6 MB)
    const size_t hBytes  = (size_t)n_rows * OUT_F * sizeof(__hip_bfloat16);
    const size_t cntOff  = align256(hBytes);
    const size_t offOff  = align256(cntOff + (size_t)n_dst * 4);
    const size_t curOff  = align256(offOff + ((size_t)n_dst + 1) * 4);
    const size_t btOff   = align256(curOff + (size_t)n_dst * 4);
    const size_t bbOff   = align256(btOff + ((size_t)nScanBlocks + 1) * 4);
    const size_t elOff   = align256(bbOff + ((size_t)nScanBlocks + 1) * 4);
    const size_t needed  = elOff + (size_t)n_edges * 4;

    __hip_bfloat16* h = (__hip_bfloat16*)d_ws;

    // K1: GEMM (persistent, 2 blocks/CU, async-staged).
    const int nTiles = n_rows / 64;           // 3125
    gemm_xw<<<512, 256, 0, stream>>>(x, W, h, nTiles);

    if (ws_size >= needed) {
        int* counts      = (int*)((char*)d_ws + cntOff);
        int* offsets     = (int*)((char*)d_ws + offOff);
        int* cursor      = (int*)((char*)d_ws + curOff);
        int* blockTotals = (int*)((char*)d_ws + btOff);
        int* blockBases  = (int*)((char*)d_ws + bbOff);
        int* elist       = (int*)((char*)d_ws + elOff);

        hipMemsetAsync(counts, 0, (size_t)n_dst * 4, stream);

        const int eBlocks = (n_edges + 255) / 256;
        count_edges<<<eBlocks, 256, 0, stream>>>(edst, counts, n_edges);
        scan_blocks<<<nScanBlocks, 256, 0, stream>>>(counts, offsets, blockTotals, n_dst);
        scan_totals<<<1, 256, 0, stream>>>(blockTotals, blockBases, nScanBlocks);
        add_base<<<nScanBlocks, 256, 0, stream>>>(offsets, cursor, blockBases, n_dst, nScanBlocks);
        fill_edges<<<eBlocks, 256, 0, stream>>>(esrc, edst, cursor, elist, n_edges);

        const int gBlocks = (n_dst + 3) / 4;
        gather_finalize<<<gBlocks, 256, 0, stream>>>(h, offsets, elist, b, out, n_dst);
    } else {
        hipMemsetAsync(out, 0, (size_t)out_size * sizeof(float), stream);
    }
}

// Round 5
// 161.735 us; speedup vs baseline: 1.1898x; 1.1898x over previous
//
#include <hip/hip_runtime.h>
#include <hip/hip_bf16.h>

#define IN_F   128
#define OUT_F  64

typedef __attribute__((ext_vector_type(8))) short short8;   // 8 bf16 (4 VGPRs)
typedef __attribute__((ext_vector_type(4))) float floatx4;  // MFMA accumulator

__device__ inline unsigned short f32_to_bf16_rne(float f) {
    unsigned int u = __float_as_uint(f);
    unsigned int r = (u + 0x7FFFu + ((u >> 16) & 1u)) >> 16;
    return (unsigned short)r;
}

// ---------------------------------------------------------------------------
// K1: h = x @ W via bf16 MFMA (16x16x32), f32 accumulate, f32 h output.
// Persistent 1024 blocks (4/CU via ~35 KB LDS), grid-stride over 64-row tiles.
// LDS: x-tile [64][136] bf16 (17.4 KB) + W^T [64][136] bf16 (17.4 KB).
// Pad 136 spreads row-base banks (4*row mod 32) -> uniform 8 lanes per
// 16B bank-group on ds_read_b128 (the 64-lane minimum, no excess conflict).
// Per wave per tile: 4 a-frag reads + 16 b-frag reads + 16 MFMA.
// Fragment maps (m89-verified): A[l&15][8*(l>>4)+j]; B[8*(l>>4)+j][l&15];
// D row=(l>>4)*4+r, col=l&15.
// ---------------------------------------------------------------------------
#define TSTRIDE 136

__global__ __launch_bounds__(256) void gemm_xw(const float* __restrict__ x,
                                               const float* __restrict__ W,
                                               float* __restrict__ h,
                                               int nTiles) {
    __shared__ unsigned short xsh[64 * TSTRIDE];   // 17.4 KB
    __shared__ unsigned short Wt[64 * TSTRIDE];    // 17.4 KB (transposed W)

    const int tid = threadIdx.x;
    const int lane = tid & 63;
    const int wave = tid >> 6;          // 0..3 -> rows [16*wave, 16*wave+16)
    const int lrow = lane & 15;
    const int lkg  = lane >> 4;         // k-group 0..3, k offset = 8*lkg

    // One-time: W (128x64 f32) -> Wt[col][k] bf16. Coalesced reads.
    {
        #pragma unroll
        for (int i = 0; i < 32; ++i) {
            const int idx = tid + i * 256;      // 0..8191
            const int k = idx >> 6;
            const int c = idx & 63;
            Wt[c * TSTRIDE + k] = f32_to_bf16_rne(W[idx]);
        }
    }

    for (int tile = blockIdx.x; tile < nTiles; tile += gridDim.x) {
        const long row0 = (long)tile * 64;

        // Stage x tile: 64x128 f32 -> bf16 in LDS. Coalesced float4 loads.
        float4 st[8];
        {
            const float4* xrow = reinterpret_cast<const float4*>(x + row0 * IN_F);
            #pragma unroll
            for (int i = 0; i < 8; ++i) st[i] = xrow[tid + i * 256];
        }
        __syncthreads();   // prev tile's readers done; orders Wt writes on iter 0
        #pragma unroll
        for (int i = 0; i < 8; ++i) {
            const int j = tid + i * 256;        // 0..2047
            const int r = j >> 5;               // row 0..63
            const int kq = (j & 31) * 4;        // k 0..124 step 4
            ushort4 v;
            v.x = f32_to_bf16_rne(st[i].x);
            v.y = f32_to_bf16_rne(st[i].y);
            v.z = f32_to_bf16_rne(st[i].z);
            v.w = f32_to_bf16_rne(st[i].w);
            *reinterpret_cast<ushort4*>(&xsh[r * TSTRIDE + kq]) = v;
        }
        __syncthreads();

        // A-fragments: 4 K-steps, 8 bf16 each (16B-aligned ds_read_b128).
        short8 a[4];
        #pragma unroll
        for (int s = 0; s < 4; ++s)
            a[s] = *reinterpret_cast<const short8*>(
                &xsh[(16 * wave + lrow) * TSTRIDE + 32 * s + 8 * lkg]);

        floatx4 acc[4];
        #pragma unroll
        for (int t = 0; t < 4; ++t) acc[t] = (floatx4){0.f, 0.f, 0.f, 0.f};

        #pragma unroll
        for (int t = 0; t < 4; ++t) {
            #pragma unroll
            for (int s = 0; s < 4; ++s) {
                const short8 b = *reinterpret_cast<const short8*>(
                    &Wt[(16 * t + lrow) * TSTRIDE + 32 * s + 8 * lkg]);
                acc[t] = __builtin_amdgcn_mfma_f32_16x16x32_bf16(a[s], b, acc[t], 0, 0, 0);
            }
        }

        // Store D: row=(lkg*4+r), col=16t+lrow; f32 (full-line coalescing).
        float* hb = h + (row0 + 16 * wave) * OUT_F;
        #pragma unroll
        for (int t = 0; t < 4; ++t)
            #pragma unroll
            for (int r = 0; r < 4; ++r)
                hb[(size_t)(lkg * 4 + r) * OUT_F + 16 * t + lrow] = acc[t][r];
    }
}

// ---------------------------------------------------------------------------
// CSR build: count -> 3-phase multi-block scan -> fill
// ---------------------------------------------------------------------------
__global__ __launch_bounds__(256) void count_edges(const int* __restrict__ edst,
                                                   int* __restrict__ counts,
                                                   int n_edges) {
    const int e = blockIdx.x * 256 + threadIdx.x;
    if (e < n_edges) atomicAdd(&counts[edst[e]], 1);
}

__global__ __launch_bounds__(256) void scan_blocks(const int* __restrict__ counts,
                                                   int* __restrict__ offsets,
                                                   int* __restrict__ blockTotals,
                                                   int n) {
    __shared__ int waveTot[4];
    const int tid = threadIdx.x;
    const int lane = tid & 63;
    const int wave = tid >> 6;
    const int i = blockIdx.x * 256 + tid;

    const int v = (i < n) ? counts[i] : 0;

    int s = v;
    #pragma unroll
    for (int off = 1; off < 64; off <<= 1) {
        const int t = __shfl_up(s, off, 64);
        if (lane >= off) s += t;
    }
    if (lane == 63) waveTot[wave] = s;
    __syncthreads();

    int base = 0;
    #pragma unroll
    for (int w = 0; w < 4; ++w)
        if (w < wave) base += waveTot[w];

    const int incl = s + base;
    if (i < n) offsets[i] = incl - v;
    if (tid == 255) blockTotals[blockIdx.x] = incl;
}

__global__ __launch_bounds__(256) void scan_totals(const int* __restrict__ blockTotals,
                                                   int* __restrict__ blockBases,
                                                   int nb) {
    __shared__ int part[256];
    const int t = threadIdx.x;
    const int v = (t < nb) ? blockTotals[t] : 0;
    part[t] = v;
    __syncthreads();
    for (int off = 1; off < 256; off <<= 1) {
        const int u = (t >= off) ? part[t - off] : 0;
        __syncthreads();
        part[t] += u;
        __syncthreads();
    }
    if (t < nb) blockBases[t] = part[t] - v;
    if (t == nb - 1) blockBases[nb] = part[t];
}

__global__ __launch_bounds__(256) void add_base(int* __restrict__ offsets,
                                                int* __restrict__ cursor,
                                                const int* __restrict__ blockBases,
                                                int n, int nb) {
    const int i = blockIdx.x * 256 + threadIdx.x;
    if (i < n) {
        const int o = offsets[i] + blockBases[blockIdx.x];
        offsets[i] = o;
        cursor[i] = o;
    }
    if (i == 0) offsets[n] = blockBases[nb];
}

__global__ __launch_bounds__(256) void fill_edges(const int* __restrict__ esrc,
                                                  const int* __restrict__ edst,
                                                  int* __restrict__ cursor,
                                                  int* __restrict__ elist,
                                                  int n_edges) {
    const int e = blockIdx.x * 256 + threadIdx.x;
    if (e < n_edges) {
        const int d = edst[e];
        const int slot = atomicAdd(&cursor[d], 1);
        elist[slot] = esrc[e];
    }
}

// ---------------------------------------------------------------------------
// K5: gather + finalize. One wave per dst, lane = feature. h is f32.
// ---------------------------------------------------------------------------
__global__ __launch_bounds__(256) void gather_finalize(const float* __restrict__ h,
                                                       const int* __restrict__ offsets,
                                                       const int* __restrict__ elist,
                                                       const float* __restrict__ b,
                                                       float* __restrict__ out,
                                                       int n_dst) {
    const int lane = threadIdx.x & 63;
    const int d = blockIdx.x * 4 + (threadIdx.x >> 6);
    if (d >= n_dst) return;

    const int e0 = offsets[d];
    const int e1 = offsets[d + 1];

    float acc = h[(size_t)d * OUT_F + lane];

    for (int base = e0; base < e1; base += 64) {
        const int cnt = min(64, e1 - base);
        const int sidx = (base + lane < e1) ? elist[base + lane] : 0;
        int j = 0;
        for (; j + 4 <= cnt; j += 4) {
            const int s0 = __shfl(sidx, j);
            const int s1 = __shfl(sidx, j + 1);
            const int s2 = __shfl(sidx, j + 2);
            const int s3 = __shfl(sidx, j + 3);
            const float v0 = h[(size_t)s0 * OUT_F + lane];
            const float v1 = h[(size_t)s1 * OUT_F + lane];
            const float v2 = h[(size_t)s2 * OUT_F + lane];
            const float v3 = h[(size_t)s3 * OUT_F + lane];
            acc += (v0 + v1) + (v2 + v3);
        }
        for (; j < cnt; ++j) {
            const int s = __shfl(sidx, j);
            acc += h[(size_t)s * OUT_F + lane];
        }
    }

    const float deg = (float)(e1 - e0);
    out[(size_t)d * OUT_F + lane] = acc / (deg + 1.0f) + b[lane];
}

static inline size_t align256(size_t v) { return (v + 255) & ~(size_t)255; }

extern "C" void kernel_launch(void* const* d_in, const int* in_sizes, int n_in,
                              void* d_out, int out_size, void* d_ws, size_t ws_size,
                              hipStream_t stream) {
    const float* x    = (const float*)d_in[0];
    const int*   esrc = (const int*)d_in[1];
    const int*   edst = (const int*)d_in[2];
    const float* W    = (const float*)d_in[3];
    const float* b    = (const float*)d_in[4];

    const int n_rows  = in_sizes[0] / IN_F;   // 200000
    const int n_edges = in_sizes[1];          // 800000
    const int n_dst   = out_size / OUT_F;     // 50000
    float* out = (float*)d_out;

    const int nScanBlocks = (n_dst + 255) / 256;            // 196

    // Workspace layout (h back to f32: 51.2 MB)
    const size_t hBytes  = (size_t)n_rows * OUT_F * sizeof(float);
    const size_t cntOff  = align256(hBytes);
    const size_t offOff  = align256(cntOff + (size_t)n_dst * 4);
    const size_t curOff  = align256(offOff + ((size_t)n_dst + 1) * 4);
    const size_t btOff   = align256(curOff + (size_t)n_dst * 4);
    const size_t bbOff   = align256(btOff + ((size_t)nScanBlocks + 1) * 4);
    const size_t elOff   = align256(bbOff + ((size_t)nScanBlocks + 1) * 4);
    const size_t needed  = elOff + (size_t)n_edges * 4;

    float* h = (float*)d_ws;

    // K1: MFMA GEMM (persistent, 4 blocks/CU).
    const int nTiles = n_rows / 64;           // 3125
    gemm_xw<<<1024, 256, 0, stream>>>(x, W, h, nTiles);

    if (ws_size >= needed) {
        int* counts      = (int*)((char*)d_ws + cntOff);
        int* offsets     = (int*)((char*)d_ws + offOff);
        int* cursor      = (int*)((char*)d_ws + curOff);
        int* blockTotals = (int*)((char*)d_ws + btOff);
        int* blockBases  = (int*)((char*)d_ws + bbOff);
        int* elist       = (int*)((char*)d_ws + elOff);

        hipMemsetAsync(counts, 0, (size_t)n_dst * 4, stream);

        const int eBlocks = (n_edges + 255) / 256;
        count_edges<<<eBlocks, 256, 0, stream>>>(edst, counts, n_edges);
        scan_blocks<<<nScanBlocks, 256, 0, stream>>>(counts, offsets, blockTotals, n_dst);
        scan_totals<<<1, 256, 0, stream>>>(blockTotals, blockBases, nScanBlocks);
        add_base<<<nScanBlocks, 256, 0, stream>>>(offsets, cursor, blockBases, n_dst, nScanBlocks);
        fill_edges<<<eBlocks, 256, 0, stream>>>(esrc, edst, cursor, elist, n_edges);

        const int gBlocks = (n_dst + 3) / 4;
        gather_finalize<<<gBlocks, 256, 0, stream>>>(h, offsets, elist, b, out, n_dst);
    } else {
        hipMemsetAsync(out, 0, (size_t)out_size * sizeof(float), stream);
    }
}

// Round 6
// 136.105 us; speedup vs baseline: 1.4139x; 1.1883x over previous
//
#include <hip/hip_runtime.h>
#include <hip/hip_bf16.h>

#define IN_F   128
#define OUT_F  64
#define N_GEMM_BLOCKS 768   // 3/CU persistent GEMM
#define N_CNT_BLOCKS  256   // 1/CU edge-count, concurrent with GEMM

typedef __attribute__((ext_vector_type(8))) short short8;   // 8 bf16 (4 VGPRs)
typedef __attribute__((ext_vector_type(4))) float floatx4;  // MFMA accumulator

__device__ inline unsigned short f32_to_bf16_rne(float f) {
    unsigned int u = __float_as_uint(f);
    unsigned int r = (u + 0x7FFFu + ((u >> 16) & 1u)) >> 16;
    return (unsigned short)r;
}
__device__ inline float bf16_to_f32(unsigned short u) {
    return __uint_as_float((unsigned int)u << 16);
}

// ---------------------------------------------------------------------------
// K1 (fused): blocks [0,768) = persistent MFMA GEMM h = x@W (bf16 in, f32
// acc, bf16 h out); blocks [768,1024) = count_edges (grid-stride atomics).
// Both roles co-resident (34.8 KB LDS -> 4 blocks/CU, grid = 1024 = 4*256).
// GEMM: LDS x-tile [64][136] bf16 + W^T [64][136] bf16; per wave per tile
// 4 a-frag + 16 b-frag ds_read_b128 + 16 MFMA. Next x-tile prefetched into
// registers before compute (T14). h store: 2B/lane, 16 lanes contiguous
// -> 32B fully-covered sectors (watch WRITE_SIZE for amplification).
// ---------------------------------------------------------------------------
#define TSTRIDE 136

__global__ __launch_bounds__(256) void gemm_count(const float* __restrict__ x,
                                                  const float* __restrict__ W,
                                                  unsigned short* __restrict__ h,
                                                  int nTiles,
                                                  const int* __restrict__ edst,
                                                  int* __restrict__ counts,
                                                  int n_edges) {
    __shared__ unsigned short xsh[64 * TSTRIDE];   // 17.4 KB
    __shared__ unsigned short Wt[64 * TSTRIDE];    // 17.4 KB

    const int tid = threadIdx.x;

    if (blockIdx.x >= N_GEMM_BLOCKS) {
        // --- count role ---
        const int stride = N_CNT_BLOCKS * 256;
        for (int e = (blockIdx.x - N_GEMM_BLOCKS) * 256 + tid; e < n_edges; e += stride)
            atomicAdd(&counts[edst[e]], 1);
        return;
    }

    // --- GEMM role ---
    const int lane = tid & 63;
    const int wave = tid >> 6;          // 0..3 -> rows [16*wave, 16*wave+16)
    const int lrow = lane & 15;
    const int lkg  = lane >> 4;         // k-group; k offset = 8*lkg

    // One-time: W (128x64 f32) -> Wt[col][k] bf16.
    {
        #pragma unroll
        for (int i = 0; i < 32; ++i) {
            const int idx = tid + i * 256;      // 0..8191
            const int k = idx >> 6;
            const int c = idx & 63;
            Wt[c * TSTRIDE + k] = f32_to_bf16_rne(W[idx]);
        }
    }

    // Prologue: stage tile0 into registers.
    int tile = blockIdx.x;
    float4 st[8];
    if (tile < nTiles) {
        const float4* xrow = reinterpret_cast<const float4*>(x + (long)tile * 64 * IN_F);
        #pragma unroll
        for (int i = 0; i < 8; ++i) st[i] = xrow[tid + i * 256];
    }

    while (tile < nTiles) {
        __syncthreads();   // prev readers of xsh done; orders Wt writes on iter 0
        #pragma unroll
        for (int i = 0; i < 8; ++i) {
            const int j = tid + i * 256;        // 0..2047
            const int r = j >> 5;               // row 0..63
            const int kq = (j & 31) * 4;        // k 0..124 step 4
            ushort4 v;
            v.x = f32_to_bf16_rne(st[i].x);
            v.y = f32_to_bf16_rne(st[i].y);
            v.z = f32_to_bf16_rne(st[i].z);
            v.w = f32_to_bf16_rne(st[i].w);
            *reinterpret_cast<ushort4*>(&xsh[r * TSTRIDE + kq]) = v;
        }
        __syncthreads();

        // Prefetch NEXT tile's x into registers; latency hides under MFMA.
        const int next = tile + N_GEMM_BLOCKS;
        if (next < nTiles) {
            const float4* xrow = reinterpret_cast<const float4*>(x + (long)next * 64 * IN_F);
            #pragma unroll
            for (int i = 0; i < 8; ++i) st[i] = xrow[tid + i * 256];
        }

        // A-fragments: 4 K-steps, 8 bf16 each.
        short8 a[4];
        #pragma unroll
        for (int s = 0; s < 4; ++s)
            a[s] = *reinterpret_cast<const short8*>(
                &xsh[(16 * wave + lrow) * TSTRIDE + 32 * s + 8 * lkg]);

        floatx4 acc[4];
        #pragma unroll
        for (int t = 0; t < 4; ++t) acc[t] = (floatx4){0.f, 0.f, 0.f, 0.f};

        #pragma unroll
        for (int t = 0; t < 4; ++t) {
            #pragma unroll
            for (int s = 0; s < 4; ++s) {
                const short8 b = *reinterpret_cast<const short8*>(
                    &Wt[(16 * t + lrow) * TSTRIDE + 32 * s + 8 * lkg]);
                acc[t] = __builtin_amdgcn_mfma_f32_16x16x32_bf16(a[s], b, acc[t], 0, 0, 0);
            }
        }

        // Store D as bf16: row=(lkg*4+r), col=16t+lrow. Per store inst the
        // 16 lrow lanes cover 32 contiguous bytes per row (full sectors).
        {
            const long row0 = (long)tile * 64;
            unsigned short* hb = h + (row0 + 16 * wave) * OUT_F;
            #pragma unroll
            for (int t = 0; t < 4; ++t)
                #pragma unroll
                for (int r = 0; r < 4; ++r)
                    hb[(size_t)(lkg * 4 + r) * OUT_F + 16 * t + lrow] =
                        f32_to_bf16_rne(acc[t][r]);
        }

        tile = next;
    }
}

// ---------------------------------------------------------------------------
// Scan chain: per-block scan -> totals scan -> add base.
// ---------------------------------------------------------------------------
__global__ __launch_bounds__(256) void scan_blocks(const int* __restrict__ counts,
                                                   int* __restrict__ offsets,
                                                   int* __restrict__ blockTotals,
                                                   int n) {
    __shared__ int waveTot[4];
    const int tid = threadIdx.x;
    const int lane = tid & 63;
    const int wave = tid >> 6;
    const int i = blockIdx.x * 256 + tid;

    const int v = (i < n) ? counts[i] : 0;

    int s = v;
    #pragma unroll
    for (int off = 1; off < 64; off <<= 1) {
        const int t = __shfl_up(s, off, 64);
        if (lane >= off) s += t;
    }
    if (lane == 63) waveTot[wave] = s;
    __syncthreads();

    int base = 0;
    #pragma unroll
    for (int w = 0; w < 4; ++w)
        if (w < wave) base += waveTot[w];

    const int incl = s + base;
    if (i < n) offsets[i] = incl - v;
    if (tid == 255) blockTotals[blockIdx.x] = incl;
}

__global__ __launch_bounds__(256) void scan_totals(const int* __restrict__ blockTotals,
                                                   int* __restrict__ blockBases,
                                                   int nb) {
    __shared__ int part[256];
    const int t = threadIdx.x;
    const int v = (t < nb) ? blockTotals[t] : 0;
    part[t] = v;
    __syncthreads();
    for (int off = 1; off < 256; off <<= 1) {
        const int u = (t >= off) ? part[t - off] : 0;
        __syncthreads();
        part[t] += u;
        __syncthreads();
    }
    if (t < nb) blockBases[t] = part[t] - v;
}

__global__ __launch_bounds__(256) void add_base(int* __restrict__ offsets,
                                                const int* __restrict__ blockBases,
                                                int n) {
    const int i = blockIdx.x * 256 + threadIdx.x;
    if (i < n) offsets[i] += blockBases[blockIdx.x];
}

// fill bumps offsets directly (start -> end); gather recovers start via counts.
__global__ __launch_bounds__(256) void fill_edges(const int* __restrict__ esrc,
                                                  const int* __restrict__ edst,
                                                  int* __restrict__ offsets,
                                                  int* __restrict__ elist,
                                                  int n_edges) {
    const int e = blockIdx.x * 256 + threadIdx.x;
    if (e < n_edges) {
        const int d = edst[e];
        const int slot = atomicAdd(&offsets[d], 1);
        elist[slot] = esrc[e];
    }
}

// ---------------------------------------------------------------------------
// K5: gather + finalize. One wave per dst, lane = feature. h is bf16
// (halves random L3 read: 800K x 128 B). 8-deep load pipeline.
// e1 = offsets[d] (post-fill end), e0 = e1 - counts[d], deg = counts[d].
// ---------------------------------------------------------------------------
__global__ __launch_bounds__(256) void gather_finalize(const unsigned short* __restrict__ h,
                                                       const int* __restrict__ offsets,
                                                       const int* __restrict__ counts,
                                                       const int* __restrict__ elist,
                                                       const float* __restrict__ b,
                                                       float* __restrict__ out,
                                                       int n_dst) {
    const int lane = threadIdx.x & 63;
    const int d = blockIdx.x * 4 + (threadIdx.x >> 6);
    if (d >= n_dst) return;

    const int cnt_d = counts[d];
    const int e1 = offsets[d];
    const int e0 = e1 - cnt_d;

    float acc = bf16_to_f32(h[(size_t)d * OUT_F + lane]);

    for (int base = e0; base < e1; base += 64) {
        const int cnt = min(64, e1 - base);
        const int sidx = (base + lane < e1) ? elist[base + lane] : 0;
        int j = 0;
        for (; j + 8 <= cnt; j += 8) {
            int s[8];
            #pragma unroll
            for (int q = 0; q < 8; ++q) s[q] = __shfl(sidx, j + q);
            float v[8];
            #pragma unroll
            for (int q = 0; q < 8; ++q)
                v[q] = bf16_to_f32(h[(size_t)s[q] * OUT_F + lane]);
            acc += ((v[0] + v[1]) + (v[2] + v[3])) + ((v[4] + v[5]) + (v[6] + v[7]));
        }
        for (; j < cnt; ++j) {
            const int s = __shfl(sidx, j);
            acc += bf16_to_f32(h[(size_t)s * OUT_F + lane]);
        }
    }

    out[(size_t)d * OUT_F + lane] = acc / ((float)cnt_d + 1.0f) + b[lane];
}

static inline size_t align256(size_t v) { return (v + 255) & ~(size_t)255; }

extern "C" void kernel_launch(void* const* d_in, const int* in_sizes, int n_in,
                              void* d_out, int out_size, void* d_ws, size_t ws_size,
                              hipStream_t stream) {
    const float* x    = (const float*)d_in[0];
    const int*   esrc = (const int*)d_in[1];
    const int*   edst = (const int*)d_in[2];
    const float* W    = (const float*)d_in[3];
    const float* b    = (const float*)d_in[4];

    const int n_rows  = in_sizes[0] / IN_F;   // 200000
    const int n_edges = in_sizes[1];          // 800000
    const int n_dst   = out_size / OUT_F;     // 50000
    float* out = (float*)d_out;

    const int nScanBlocks = (n_dst + 255) / 256;            // 196

    // Workspace layout (h bf16: 25.6 MB)
    const size_t hBytes  = (size_t)n_rows * OUT_F * sizeof(unsigned short);
    const size_t cntOff  = align256(hBytes);
    const size_t offOff  = align256(cntOff + (size_t)n_dst * 4);
    const size_t btOff   = align256(offOff + ((size_t)n_dst + 1) * 4);
    const size_t bbOff   = align256(btOff + ((size_t)nScanBlocks + 1) * 4);
    const size_t elOff   = align256(bbOff + ((size_t)nScanBlocks + 1) * 4);
    const size_t needed  = elOff + (size_t)n_edges * 4;

    unsigned short* h = (unsigned short*)d_ws;

    if (ws_size >= needed) {
        int* counts      = (int*)((char*)d_ws + cntOff);
        int* offsets     = (int*)((char*)d_ws + offOff);
        int* blockTotals = (int*)((char*)d_ws + btOff);
        int* blockBases  = (int*)((char*)d_ws + bbOff);
        int* elist       = (int*)((char*)d_ws + elOff);

        hipMemsetAsync(counts, 0, (size_t)n_dst * 4, stream);

        // K1: fused GEMM (768 persistent blocks) + count (256 blocks).
        const int nTiles = n_rows / 64;       // 3125
        gemm_count<<<N_GEMM_BLOCKS + N_CNT_BLOCKS, 256, 0, stream>>>(
            x, W, h, nTiles, edst, counts, n_edges);

        scan_blocks<<<nScanBlocks, 256, 0, stream>>>(counts, offsets, blockTotals, n_dst);
        scan_totals<<<1, 256, 0, stream>>>(blockTotals, blockBases, nScanBlocks);
        add_base<<<nScanBlocks, 256, 0, stream>>>(offsets, blockBases, n_dst);

        const int eBlocks = (n_edges + 255) / 256;
        fill_edges<<<eBlocks, 256, 0, stream>>>(esrc, edst, offsets, elist, n_edges);

        const int gBlocks = (n_dst + 3) / 4;
        gather_finalize<<<gBlocks, 256, 0, stream>>>(h, offsets, counts, elist, b, out, n_dst);
    } else {
        hipMemsetAsync(out, 0, (size_t)out_size * sizeof(float), stream);
    }
}